// Round 9
// baseline (3607.722 us; speedup 1.0000x reference)
//
#include <hip/hip_runtime.h>
#include <hip/hip_bf16.h>

// Problem sizes
#define Bb 128
#define Tt 1024
#define Dd 256
#define Hh 512
#define G4 2048
#define Oo 256

#define NBG 8        // batch groups (16 rows each), one per XCD by construction
#define WPB 8        // worker wgs per batch group
#define NWG_LAUNCH 128  // launch 2x needed; surplus wgs exit after ticket claim
#define BLOCK 512    // 8 waves

#define SPIN_CAP (1u << 20)   // escape valve: never hang the harness

typedef __attribute__((ext_vector_type(8))) short short8;
typedef __attribute__((ext_vector_type(4))) float f32x4;
typedef __attribute__((ext_vector_type(4))) unsigned int u32x4;
typedef unsigned long long u64;

// ws layout: [tickets: 8 x 64B @0][cnt: 8 x 128B @2048][hbuf: 2*128*512 bf16 @4096]
#define TICK_OFF 0
#define CNT_OFF  2048
#define HBUF_OFF 4096
#define WS_ZERO_BYTES (4096 + Bb*Hh*2)   // tickets + counters + hbuf half 0

__device__ __forceinline__ short f2bf(float f) {
  __hip_bfloat16 h = __float2bfloat16(f);
  return *reinterpret_cast<short*>(&h);
}
__device__ __forceinline__ float sigm(float x) {
  return __builtin_amdgcn_rcpf(1.f + __expf(-x));
}
__device__ __forceinline__ float tanh_(float x) {
  return fmaf(2.f, __builtin_amdgcn_rcpf(1.f + __expf(-2.f * x)), -1.f);
}

#define MFMA16(A, B, C) __builtin_amdgcn_mfma_f32_16x16x32_bf16((A), (B), (C), 0, 0, 0)

__global__ __launch_bounds__(BLOCK, 2) void lstm_seq(
    const float* __restrict__ X, const float* __restrict__ Wi,
    const float* __restrict__ Wh, const float* __restrict__ bias,
    char* hbuf, int* cnts, int* tickets)
{
  __shared__ char sH[16 * 1024];   // h tile (bf16, XOR-swizzled)
  __shared__ char sX[16 * 512];    // x tile (bf16, XOR-swizzled)
  __shared__ int sSlot;

  const int tid  = threadIdx.x;
  const int w    = tid >> 6;      // wave 0..7
  const int lane = tid & 63;

  // ---- Role claim: all 8 workers of a bg are on XCD bg BY CONSTRUCTION.
  int myxcc;
  asm volatile("s_getreg_b32 %0, hwreg(HW_REG_XCC_ID)" : "=s"(myxcc));
  myxcc &= 7;
  if (tid == 0) {
    sSlot = __hip_atomic_fetch_add(&tickets[myxcc * 16], 1,
                                   __ATOMIC_RELAXED, __HIP_MEMORY_SCOPE_AGENT);
  }
  __syncthreads();
  const int gjw = sSlot;          // col-group: h-cols [gjw*64, +64)
  if (gjw >= WPB) return;         // surplus wg: exit (wg-uniform)
  const int bg = myxcc;           // batch group == this XCD
  int* cnt = cnts + bg * 32;      // 128B apart per bg

  // ---- Persistent weight B-fragments: wf[nt][kk], nt0 = gates i,f ; nt1 = g,o
  // B lane map (16x16x32): col = lane&15, k = kk*32 + (lane>>4)*8 + i
  short8 wf[2][24];
  float bv[2];
#pragma unroll
  for (int nt = 0; nt < 2; ++nt) {
    int c = nt * 16 + (lane & 15);
    int gate = c >> 3, jj0 = c & 7;
    int colg = gate * Hh + gjw * 64 + w * 8 + jj0;
    bv[nt] = bias[colg];
#pragma unroll
    for (int kk = 0; kk < 24; ++kk) {
      short8 f;
#pragma unroll
      for (int i = 0; i < 8; ++i) {
        int k = kk * 32 + (lane >> 4) * 8 + i;
        float v = (k < Hh) ? Wh[(size_t)k * G4 + colg]
                           : Wi[(size_t)(k - Hh) * G4 + colg];
        f[i] = f2bf(v);
      }
      wf[nt][kk] = f;
    }
  }

  const int cjj  = lane & 15;        // MFMA col / A row
  const int kgrp = lane >> 4;        // 0..3
  const int arow = cjj;
  const int aswz = (arow & 7) << 4;
  const int hi8  = (cjj >> 3) & 1;   // 0: owns i,g cols ; 1: owns f,o cols
  const int jj   = cjj & 7;
  const int orow = kgrp * 4 + hi8 * 2;  // this lane's 2 rows: orow, orow+1
  float cpr[2] = {0.f, 0.f};

  // h-staging thread mapping (2 x 16B per thread)
  const int hrow0 = tid >> 6,         hoff0 = tid & 63;          // c = tid
  const int hrow1 = (tid + 512) >> 6, hoff1 = tid & 63;          // c = tid+512

  for (int s = 1; s <= Tt; ++s) {
    const char* hread  = hbuf + (size_t)((s - 1) & 1) * (Bb * Hh * 2);
    char*       hwrite = hbuf + (size_t)(s & 1) * (Bb * Hh * 2);

    // ---- 1. stage x_t (plain cached loads, issued before the poll so their
    // latency overlaps the producer wait): 16 rows x 256 f32
    {
      int row = tid >> 5, seg = tid & 31;
      const float* xp = X + ((size_t)(bg * 16 + row) * Tt + (s - 1)) * Dd + seg * 8;
      f32x4 x0 = *reinterpret_cast<const f32x4*>(xp);
      f32x4 x1 = *reinterpret_cast<const f32x4*>(xp + 4);
      short8 xb;
      xb[0] = f2bf(x0[0]); xb[1] = f2bf(x0[1]); xb[2] = f2bf(x0[2]); xb[3] = f2bf(x0[3]);
      xb[4] = f2bf(x1[0]); xb[5] = f2bf(x1[1]); xb[6] = f2bf(x1[2]); xb[7] = f2bf(x1[3]);
      *reinterpret_cast<short8*>(sX + row * 512 + ((seg * 16) ^ ((row & 7) << 4))) = xb;
    }

    // ---- 2. wait for the 8 producers of this bg (step s-1). Non-idempotent
    // RMW executes at the XCD L2 atomic point (same point as producer +1s).
    if (s > 1 && tid == 0) {
      const int tgt = WPB * (s - 1);
      unsigned spin = 0;
      while ((int)(__hip_atomic_fetch_add((unsigned*)cnt, 0x10000u,
                                          __ATOMIC_RELAXED,
                                          __HIP_MEMORY_SCOPE_WORKGROUP) & 0xFFFFu) < tgt
             && ++spin < SPIN_CAP) {}
    }
    __syncthreads();

    // ---- 3. invalidate L1 (stale h lines from step s-2), issue the two
    // cooperative h(s-1) loads (16KB tile from the shared XCD L2) into temps.
    asm volatile("buffer_inv sc0" ::: "memory");
    f32x4 ht0 = *reinterpret_cast<const f32x4*>(
        hread + (size_t)(bg * 16 + hrow0) * 1024 + hoff0 * 16);
    f32x4 ht1 = *reinterpret_cast<const f32x4*>(
        hread + (size_t)(bg * 16 + hrow1) * 1024 + hoff1 * 16);

    // ---- 4. x-part MFMA (k = 512..767) — runs under the h-load latency
    f32x4 acc0, acc1;
#pragma unroll
    for (int m = 0; m < 4; ++m) { acc0[m] = bv[0]; acc1[m] = bv[1]; }
#pragma unroll
    for (int kk = 0; kk < 8; ++kk) {
      short8 a = *reinterpret_cast<const short8*>(
          sX + arow * 512 + ((kk * 64 + kgrp * 16) ^ aswz));
      acc0 = MFMA16(a, wf[0][16 + kk], acc0);
      acc1 = MFMA16(a, wf[1][16 + kk], acc1);
    }

    // ---- 5. write h temps into sH (XOR-swizzled), barrier
    *reinterpret_cast<f32x4*>(
        sH + hrow0 * 1024 + ((hoff0 * 16) ^ ((hrow0 & 7) << 4))) = ht0;
    *reinterpret_cast<f32x4*>(
        sH + hrow1 * 1024 + ((hoff1 * 16) ^ ((hrow1 & 7) << 4))) = ht1;
    __syncthreads();

    // ---- 6. h-part MFMA (k = 0..511)
#pragma unroll
    for (int kk = 0; kk < 16; ++kk) {
      short8 a = *reinterpret_cast<const short8*>(
          sH + arow * 1024 + ((kk * 64 + kgrp * 16) ^ aswz));
      acc0 = MFMA16(a, wf[0][kk], acc0);
      acc1 = MFMA16(a, wf[1][kk], acc1);
    }

    // ---- 7. in-register epilogue: pairs (lane, lane^8) swap i/f and g/o
    float o0[4], o1[4];
#pragma unroll
    for (int m = 0; m < 4; ++m) {
      o0[m] = __shfl_xor(acc0[m], 8);
      o1[m] = __shfl_xor(acc1[m], 8);
    }
    float hv[2];
#pragma unroll
    for (int q = 0; q < 2; ++q) {
      int m = hi8 * 2 + q;
      float iv = hi8 ? o0[m]   : acc0[m];
      float fv = hi8 ? acc0[m] : o0[m];
      float gv = hi8 ? o1[m]   : acc1[m];
      float ov = hi8 ? acc1[m] : o1[m];
      float ig = sigm(iv), fg = sigm(fv), gg = tanh_(gv), og = sigm(ov);
      float c = fg * cpr[q] + ig * gg;
      cpr[q] = c;
      hv[q] = og * tanh_(c);
    }

    // ---- 8. pack 8 lanes' bf16 (cols jj=0..7 of rows orow/orow+1) into 16B
    // via 3 shfl_xor rounds; lane jj==0 stores two 16B rows (write-through L2).
    {
      __hip_bfloat16 hb0 = __float2bfloat16(hv[0]);
      __hip_bfloat16 hb1 = __float2bfloat16(hv[1]);
      unsigned p0 = (unsigned)*reinterpret_cast<unsigned short*>(&hb0);
      unsigned p1 = (unsigned)*reinterpret_cast<unsigned short*>(&hb1);
      unsigned q0 = __shfl_xor(p0, 1), q1 = __shfl_xor(p1, 1);
      unsigned lo, hi;
      lo = (jj & 1) ? q0 : p0; hi = (jj & 1) ? p0 : q0;
      p0 = (lo & 0xFFFFu) | (hi << 16);
      lo = (jj & 1) ? q1 : p1; hi = (jj & 1) ? p1 : q1;
      p1 = (lo & 0xFFFFu) | (hi << 16);
      unsigned r0 = __shfl_xor(p0, 2), r1 = __shfl_xor(p1, 2);
      unsigned a0 = (jj & 2) ? r0 : p0, a1 = (jj & 2) ? p0 : r0;
      unsigned b0 = (jj & 2) ? r1 : p1, b1 = (jj & 2) ? p1 : r1;
      unsigned s0 = __shfl_xor(a0, 4), s1 = __shfl_xor(a1, 4);
      unsigned t0 = __shfl_xor(b0, 4), t1 = __shfl_xor(b1, 4);
      u32x4 v0, v1;
      if ((jj & 4) == 0) {
        v0[0] = a0; v0[1] = a1; v0[2] = s0; v0[3] = s1;
        v1[0] = b0; v1[1] = b1; v1[2] = t0; v1[3] = t1;
      } else {
        v0[0] = s0; v0[1] = s1; v0[2] = a0; v0[3] = a1;
        v1[0] = t0; v1[1] = t1; v1[2] = b0; v1[3] = b1;
      }
      if (jj == 0) {
        char* hw = hwrite + ((size_t)(bg * 16 + orow) * Hh + gjw * 64 + w * 8) * 2;
        *reinterpret_cast<u32x4*>(hw) = v0;
        *reinterpret_cast<u32x4*>(hw + Hh * 2) = v1;
      }
    }
    __syncthreads();  // drains vmcnt per wave => h stores complete at L2

    // ---- 9. signal
    if (tid == 0) {
      (void)__hip_atomic_fetch_add(cnt, 1, __ATOMIC_RELAXED,
                                   __HIP_MEMORY_SCOPE_WORKGROUP);
    }
  }
}

__global__ void out_dense(const __hip_bfloat16* __restrict__ hT,
                          const float* __restrict__ Wd,
                          const float* __restrict__ bd,
                          float* __restrict__ out)
{
  // lstm_seq's end-of-kernel release writes dirty L2 back; plain loads ok.
  __shared__ float hrow[Hh];
  int b = blockIdx.x;
  int o = threadIdx.x;
  for (int k = o; k < Hh; k += Oo)
    hrow[k] = __bfloat162float(hT[(size_t)b * Hh + k]);
  __syncthreads();
  float acc = bd[o];
  for (int k = 0; k < Hh; ++k)
    acc = fmaf(hrow[k], Wd[(size_t)k * Oo + o], acc);
  out[(size_t)b * Oo + o] = acc;
}

extern "C" void kernel_launch(void* const* d_in, const int* in_sizes, int n_in,
                              void* d_out, int out_size, void* d_ws, size_t ws_size,
                              hipStream_t stream) {
  (void)in_sizes; (void)n_in; (void)out_size; (void)ws_size;
  const float* X  = (const float*)d_in[0];
  const float* Wi = (const float*)d_in[1];
  const float* Wh = (const float*)d_in[2];
  const float* b  = (const float*)d_in[3];
  const float* Wd = (const float*)d_in[4];
  const float* bd = (const float*)d_in[5];
  float* out = (float*)d_out;

  char* ws = (char*)d_ws;
  int* tickets = (int*)(ws + TICK_OFF);
  int* cnts    = (int*)(ws + CNT_OFF);
  char* hbuf   = ws + HBUF_OFF;

  // zero tickets, counters, and h(0) every launch (graph-replay deterministic)
  hipMemsetAsync(d_ws, 0, WS_ZERO_BYTES, stream);
  lstm_seq<<<NWG_LAUNCH, BLOCK, 0, stream>>>(X, Wi, Wh, b, hbuf, cnts, tickets);
  out_dense<<<Bb, Oo, 0, stream>>>((const __hip_bfloat16*)hbuf, Wd, bd, out);
}

// Round 10
// 2684.710 us; speedup vs baseline: 1.3438x; 1.3438x over previous
//
#include <hip/hip_runtime.h>
#include <hip/hip_bf16.h>

// Problem sizes
#define Bb 128
#define Tt 1024
#define Dd 256
#define Hh 512
#define G4 2048
#define Oo 256

#define NBG 8        // batch groups (16 rows each), one per XCD by construction
#define WPB 16       // worker wgs per batch group (32 h-cols each)
#define NWG_LAUNCH 256  // launch 2x needed; surplus wgs exit after ticket claim
#define BLOCK 512    // 8 waves

#define SPIN_CAP (1u << 20)   // escape valve: never hang the harness

typedef __attribute__((ext_vector_type(8))) short short8;
typedef __attribute__((ext_vector_type(4))) float f32x4;
typedef unsigned long long u64;

// ws layout: [tickets: 8 x 64B @0][cnt: 8 x 128B @2048][hbuf: 2*128*512 bf16 @4096]
#define TICK_OFF 0
#define CNT_OFF  2048
#define HBUF_OFF 4096
#define WS_ZERO_BYTES (4096 + Bb*Hh*2)   // tickets + counters + hbuf half 0

__device__ __forceinline__ short f2bf(float f) {
  __hip_bfloat16 h = __float2bfloat16(f);
  return *reinterpret_cast<short*>(&h);
}
__device__ __forceinline__ float sigm(float x) {
  return __builtin_amdgcn_rcpf(1.f + __expf(-x));
}
__device__ __forceinline__ float tanh_(float x) {
  return fmaf(2.f, __builtin_amdgcn_rcpf(1.f + __expf(-2.f * x)), -1.f);
}

#define MFMA16(A, B, C) __builtin_amdgcn_mfma_f32_16x16x32_bf16((A), (B), (C), 0, 0, 0)

__global__ __launch_bounds__(BLOCK, 2) void lstm_seq(
    const float* __restrict__ X, const float* __restrict__ Wi,
    const float* __restrict__ Wh, const float* __restrict__ bias,
    char* hbuf, int* cnts, int* tickets)
{
  __shared__ char sH[16 * 1024];            // h tile (bf16, XOR-swizzled)
  __shared__ char sX[16 * 512];             // x tile (bf16, XOR-swizzled)
  __shared__ unsigned short hstage[16][40]; // wg h-slice (16 rows x 32 cols), padded
  __shared__ int sSlot;

  const int tid  = threadIdx.x;
  const int w    = tid >> 6;      // wave 0..7
  const int lane = tid & 63;

  // ---- Role claim: all 16 workers of a bg are on XCD bg BY CONSTRUCTION.
  int myxcc;
  asm volatile("s_getreg_b32 %0, hwreg(HW_REG_XCC_ID)" : "=s"(myxcc));
  myxcc &= 7;
  if (tid == 0) {
    sSlot = __hip_atomic_fetch_add(&tickets[myxcc * 16], 1,
                                   __ATOMIC_RELAXED, __HIP_MEMORY_SCOPE_AGENT);
  }
  __syncthreads();
  const int gjw = sSlot;          // col-group: h-cols [gjw*32, +32)
  if (gjw >= WPB) return;         // surplus wg: exit (wg-uniform)
  const int bg = myxcc;           // batch group == this XCD
  int* cnt = cnts + bg * 32;      // 128B apart per bg

  // ---- Persistent weight B-fragments: ONE n-tile per wave -> wf fits in regs
  // by construction (24 x short8 = 96 regs/lane).
  // Lane cjj: gate = cjj>>2, c4 = cjj&3 -> col = gate*Hh + gjw*32 + w*4 + c4.
  // B lane map (16x16x32): col = lane&15, k = kk*32 + (lane>>4)*8 + i
  const int cjj  = lane & 15;
  const int kgrp = lane >> 4;        // 0..3
  const int gate = cjj >> 2;
  const int c4   = cjj & 3;
  const int colg = gate * Hh + gjw * 32 + w * 4 + c4;

  short8 wf[24];
#pragma unroll
  for (int kk = 0; kk < 24; ++kk) {
    short8 f;
#pragma unroll
    for (int i = 0; i < 8; ++i) {
      int k = kk * 32 + kgrp * 8 + i;
      float v = (k < Hh) ? Wh[(size_t)k * G4 + colg]
                         : Wi[(size_t)(k - Hh) * G4 + colg];
      f[i] = f2bf(v);
    }
    wf[kk] = f;
  }
  const float bvv = bias[colg];

  const int arow = cjj;              // MFMA A row
  const int aswz = (arow & 7) << 4;
  float cpr[4] = {0.f, 0.f, 0.f, 0.f};  // c-state rows kgrp*4+m (gate-0 lanes)

  for (int s = 1; s <= Tt; ++s) {
    const char* hread  = hbuf + (size_t)((s - 1) & 1) * (Bb * Hh * 2);
    char*       hwrite = hbuf + (size_t)(s & 1) * (Bb * Hh * 2);

    // ---- 1. stage x_t (plain cached loads, issued before the poll so their
    // latency overlaps the producer wait): 16 rows x 256 f32
    {
      int row = tid >> 5, seg = tid & 31;
      const float* xp = X + ((size_t)(bg * 16 + row) * Tt + (s - 1)) * Dd + seg * 8;
      f32x4 x0 = *reinterpret_cast<const f32x4*>(xp);
      f32x4 x1 = *reinterpret_cast<const f32x4*>(xp + 4);
      short8 xb;
      xb[0] = f2bf(x0[0]); xb[1] = f2bf(x0[1]); xb[2] = f2bf(x0[2]); xb[3] = f2bf(x0[3]);
      xb[4] = f2bf(x1[0]); xb[5] = f2bf(x1[1]); xb[6] = f2bf(x1[2]); xb[7] = f2bf(x1[3]);
      *reinterpret_cast<short8*>(sX + row * 512 + ((seg * 16) ^ ((row & 7) << 4))) = xb;
    }

    // ---- 2. wait for the 16 producers of this bg (step s-1). Non-idempotent
    // RMW executes at the XCD L2 atomic point (same point as producer +1s).
    if (s > 1 && tid == 0) {
      const int tgt = WPB * (s - 1);
      unsigned spin = 0;
      while ((int)(__hip_atomic_fetch_add((unsigned*)cnt, 0x10000u,
                                          __ATOMIC_RELAXED,
                                          __HIP_MEMORY_SCOPE_WORKGROUP) & 0xFFFFu) < tgt
             && ++spin < SPIN_CAP) {}
    }
    __syncthreads();

    // ---- 3. invalidate L1 (stale h lines from step s-2), cooperative
    // coalesced h(s-1) staging: 16 rows x 512 bf16 = 16KB from XCD L2.
    asm volatile("buffer_inv sc0" ::: "memory");
#pragma unroll
    for (int q = 0; q < 2; ++q) {
      int c = tid + q * 512, row = c >> 6, off = c & 63;
      f32x4 v = *reinterpret_cast<const f32x4*>(
          hread + (size_t)(bg * 16 + row) * 1024 + off * 16);
      *reinterpret_cast<f32x4*>(sH + row * 1024 + ((off * 16) ^ ((row & 7) << 4))) = v;
    }
    __syncthreads();

    // ---- 4. MFMA: 24 k-steps, single n-tile
    f32x4 acc;
#pragma unroll
    for (int m = 0; m < 4; ++m) acc[m] = bvv;
#pragma unroll
    for (int kk = 0; kk < 16; ++kk) {   // h part, k = 0..511
      short8 a = *reinterpret_cast<const short8*>(
          sH + arow * 1024 + ((kk * 64 + kgrp * 16) ^ aswz));
      acc = MFMA16(a, wf[kk], acc);
    }
#pragma unroll
    for (int kk = 0; kk < 8; ++kk) {    // x part, k = 512..767
      short8 a = *reinterpret_cast<const short8*>(
          sX + arow * 512 + ((kk * 64 + kgrp * 16) ^ aswz));
      acc = MFMA16(a, wf[16 + kk], acc);
    }

    // ---- 5. gather gates via 3 shfl_xor rounds (within 16-lane groups):
    // lane cjj<4 ends with i=acc, f=r1, g=r2, o=r3 for its column.
    float r1[4], r2[4], r3[4];
#pragma unroll
    for (int m = 0; m < 4; ++m) {
      r1[m] = __shfl_xor(acc[m], 4);
      r2[m] = __shfl_xor(acc[m], 8);
      r3[m] = __shfl_xor(r1[m], 8);
    }
    if (cjj < 4) {   // 16 productive lanes per wave: 16 rows x this lane's col
#pragma unroll
      for (int m = 0; m < 4; ++m) {
        float ig = sigm(acc[m]), fg = sigm(r1[m]);
        float gg = tanh_(r2[m]), og = sigm(r3[m]);
        float c = fg * cpr[m] + ig * gg;
        cpr[m] = c;
        float hh = og * tanh_(c);
        __hip_bfloat16 hb = __float2bfloat16(hh);
        hstage[kgrp * 4 + m][w * 4 + c4] = *reinterpret_cast<unsigned short*>(&hb);
      }
    }
    __syncthreads();

    // ---- 6. store h slice: 16 rows x 32 cols x 2B (64 threads x 16B, each
    // row's 64B line covered by 4 threads; write-through L1 -> shared XCD L2)
    if (tid < 64) {
      int row = tid >> 2, chunk = tid & 3;
      f32x4 v = *reinterpret_cast<const f32x4*>(&hstage[row][chunk * 8]);
      *reinterpret_cast<f32x4*>(
          hwrite + ((size_t)(bg * 16 + row) * Hh + gjw * 32 + chunk * 8) * 2) = v;
    }
    __syncthreads();  // drains vmcnt per wave => h stores complete at L2

    // ---- 7. signal
    if (tid == 0) {
      (void)__hip_atomic_fetch_add(cnt, 1, __ATOMIC_RELAXED,
                                   __HIP_MEMORY_SCOPE_WORKGROUP);
    }
  }
}

__global__ void out_dense(const __hip_bfloat16* __restrict__ hT,
                          const float* __restrict__ Wd,
                          const float* __restrict__ bd,
                          float* __restrict__ out)
{
  // lstm_seq's end-of-kernel release writes dirty L2 back; plain loads ok.
  __shared__ float hrow[Hh];
  int b = blockIdx.x;
  int o = threadIdx.x;
  for (int k = o; k < Hh; k += Oo)
    hrow[k] = __bfloat162float(hT[(size_t)b * Hh + k]);
  __syncthreads();
  float acc = bd[o];
  for (int k = 0; k < Hh; ++k)
    acc = fmaf(hrow[k], Wd[(size_t)k * Oo + o], acc);
  out[(size_t)b * Oo + o] = acc;
}

extern "C" void kernel_launch(void* const* d_in, const int* in_sizes, int n_in,
                              void* d_out, int out_size, void* d_ws, size_t ws_size,
                              hipStream_t stream) {
  (void)in_sizes; (void)n_in; (void)out_size; (void)ws_size;
  const float* X  = (const float*)d_in[0];
  const float* Wi = (const float*)d_in[1];
  const float* Wh = (const float*)d_in[2];
  const float* b  = (const float*)d_in[3];
  const float* Wd = (const float*)d_in[4];
  const float* bd = (const float*)d_in[5];
  float* out = (float*)d_out;

  char* ws = (char*)d_ws;
  int* tickets = (int*)(ws + TICK_OFF);
  int* cnts    = (int*)(ws + CNT_OFF);
  char* hbuf   = ws + HBUF_OFF;

  // zero tickets, counters, and h(0) every launch (graph-replay deterministic)
  hipMemsetAsync(d_ws, 0, WS_ZERO_BYTES, stream);
  lstm_seq<<<NWG_LAUNCH, BLOCK, 0, stream>>>(X, Wi, Wh, b, hbuf, cnts, tickets);
  out_dense<<<Bb, Oo, 0, stream>>>((const __hip_bfloat16*)hbuf, Wd, bd, out);
}

// Round 13
// 2658.537 us; speedup vs baseline: 1.3570x; 1.0098x over previous
//
#include <hip/hip_runtime.h>
#include <hip/hip_bf16.h>

// Problem sizes
#define Bb 128
#define Tt 1024
#define Dd 256
#define Hh 512
#define G4 2048
#define Oo 256

#define NBG 8        // batch groups (16 rows each), one per XCD by construction
#define WPB 16       // worker wgs per batch group (32 h-cols each)
#define NWG_LAUNCH 256  // launch 2x needed; surplus wgs exit after ticket claim
#define BLOCK 512    // 8 waves

#define SPIN_CAP (1u << 16)   // PER-STEP spin cap (with s_sleep backoff)

typedef __attribute__((ext_vector_type(8))) short short8;
typedef __attribute__((ext_vector_type(4))) float f32x4;
typedef unsigned long long u64;

// ws layout: [tickets: 8 x 64B @0][cnt: 8 x 128B @2048][hbuf: 2*128*512 bf16 @4096]
#define TICK_OFF 0
#define CNT_OFF  2048
#define HBUF_OFF 4096
#define WS_ZERO_BYTES (4096 + Bb*Hh*2)   // tickets + counters + hbuf half 0

__device__ __forceinline__ short f2bf(float f) {
  __hip_bfloat16 h = __float2bfloat16(f);
  return *reinterpret_cast<short*>(&h);
}
__device__ __forceinline__ float sigm(float x) {
  return __builtin_amdgcn_rcpf(1.f + __expf(-x));
}
__device__ __forceinline__ float tanh_(float x) {
  return fmaf(2.f, __builtin_amdgcn_rcpf(1.f + __expf(-2.f * x)), -1.f);
}

#define MFMA16(A, B, C) __builtin_amdgcn_mfma_f32_16x16x32_bf16((A), (B), (C), 0, 0, 0)

__global__ __launch_bounds__(BLOCK, 2) void lstm_seq(
    const float* __restrict__ X, const float* __restrict__ Wi,
    const float* __restrict__ Wh, const float* __restrict__ bias,
    char* hbuf, int* cnts, int* tickets)
{
  __shared__ char sH[16 * 1024];            // h tile (bf16, XOR-swizzled)
  __shared__ char sX[16 * 512];             // x tile (bf16, XOR-swizzled)
  __shared__ unsigned short hstage[16][40]; // wg h-slice (16 rows x 32 cols), padded
  __shared__ int sSlot;

  const int tid  = threadIdx.x;
  const int w    = tid >> 6;      // wave 0..7
  const int lane = tid & 63;

  // ---- Role claim: all 16 workers of a bg are on XCD bg BY CONSTRUCTION.
  int myxcc;
  asm volatile("s_getreg_b32 %0, hwreg(HW_REG_XCC_ID)" : "=s"(myxcc));
  myxcc &= 7;
  if (tid == 0) {
    sSlot = __hip_atomic_fetch_add(&tickets[myxcc * 16], 1,
                                   __ATOMIC_RELAXED, __HIP_MEMORY_SCOPE_AGENT);
  }
  __syncthreads();
  const int gjw = sSlot;          // col-group: h-cols [gjw*32, +32)
  if (gjw >= WPB) return;         // surplus wg: exit (wg-uniform)
  const int bg = myxcc;           // batch group == this XCD
  int* cnt = cnts + bg * 32;      // 128B apart per bg

  // ---- Persistent weight B-fragments: ONE n-tile per wave (24 x short8).
  // Lane cjj: gate = cjj>>2, c4 = cjj&3 -> col = gate*Hh + gjw*32 + w*4 + c4.
  // B lane map (16x16x32): col = lane&15, k = kk*32 + (lane>>4)*8 + i
  const int cjj  = lane & 15;
  const int kgrp = lane >> 4;        // 0..3
  const int gate = cjj >> 2;
  const int c4   = cjj & 3;
  const int colg = gate * Hh + gjw * 32 + w * 4 + c4;

  short8 wf[24];
#pragma unroll
  for (int kk = 0; kk < 24; ++kk) {
    short8 f;
#pragma unroll
    for (int i = 0; i < 8; ++i) {
      int k = kk * 32 + kgrp * 8 + i;
      float v = (k < Hh) ? Wh[(size_t)k * G4 + colg]
                         : Wi[(size_t)(k - Hh) * G4 + colg];
      f[i] = f2bf(v);
    }
    wf[kk] = f;
  }
  const float bvv = bias[colg];

  const int arow = cjj;              // MFMA A row
  const int aswz = (arow & 7) << 4;
  float cpr[4] = {0.f, 0.f, 0.f, 0.f};  // c-state rows kgrp*4+m (gate-0 lanes)

  // ---- x prefetch (2-step pipeline in registers)
  const int xrow = tid >> 5, xseg = tid & 31;   // wg covers 16 rows x 256 f32
  const float* xbase = X + (size_t)(bg * 16 + xrow) * Tt * Dd + xseg * 8;
  f32x4 xA0 = *reinterpret_cast<const f32x4*>(xbase);
  f32x4 xA1 = *reinterpret_cast<const f32x4*>(xbase + 4);
  f32x4 xB0 = *reinterpret_cast<const f32x4*>(xbase + Dd);
  f32x4 xB1 = *reinterpret_cast<const f32x4*>(xbase + Dd + 4);

  auto STEP = [&](int s, f32x4& xv0, f32x4& xv1) {
    const char* hread  = hbuf + (size_t)((s - 1) & 1) * (Bb * Hh * 2);
    char*       hwrite = hbuf + (size_t)(s & 1) * (Bb * Hh * 2);

    // ---- 1. stage x_t into sX from regs prefetched 2 steps ago (reg->LDS;
    // the global x load is no longer on the per-step critical path)
    {
      short8 xb;
      xb[0] = f2bf(xv0[0]); xb[1] = f2bf(xv0[1]); xb[2] = f2bf(xv0[2]); xb[3] = f2bf(xv0[3]);
      xb[4] = f2bf(xv1[0]); xb[5] = f2bf(xv1[1]); xb[6] = f2bf(xv1[2]); xb[7] = f2bf(xv1[3]);
      *reinterpret_cast<short8*>(sX + xrow * 512 + ((xseg * 16) ^ ((xrow & 7) << 4))) = xb;
    }

    // ---- 2. wait for the 16 producers of this bg (step s-1). Non-idempotent
    // RMW executes at the XCD L2 atomic point; s_sleep backoff keeps the flag
    // line free so producer increments land without queueing. PER-STEP cap.
    if (s > 1 && tid == 0) {
      const int tgt = WPB * (s - 1);
      unsigned spin = 0;
      while ((int)(__hip_atomic_fetch_add((unsigned*)cnt, 0x10000u,
                                          __ATOMIC_RELAXED,
                                          __HIP_MEMORY_SCOPE_WORKGROUP) & 0xFFFFu) < tgt
             && ++spin < SPIN_CAP) {
        __builtin_amdgcn_s_sleep(2);
      }
    }
    __syncthreads();

    // ---- 3. invalidate L1 (stale h lines from step s-2), cooperative
    // coalesced h(s-1) staging: 16 rows x 512 bf16 = 16KB from XCD L2.
    asm volatile("buffer_inv sc0" ::: "memory");
#pragma unroll
    for (int q = 0; q < 2; ++q) {
      int c = tid + q * 512, row = c >> 6, off = c & 63;
      f32x4 v = *reinterpret_cast<const f32x4*>(
          hread + (size_t)(bg * 16 + row) * 1024 + off * 16);
      *reinterpret_cast<f32x4*>(sH + row * 1024 + ((off * 16) ^ ((row & 7) << 4))) = v;
    }
    __syncthreads();

    // ---- 4. MFMA: 24 k-steps, single n-tile, two independent acc chains
    f32x4 acc_a, acc_b;
#pragma unroll
    for (int m = 0; m < 4; ++m) { acc_a[m] = bvv; acc_b[m] = 0.f; }
#pragma unroll
    for (int kk = 0; kk < 8; ++kk) {    // h part, k = 0..255
      short8 a = *reinterpret_cast<const short8*>(
          sH + arow * 1024 + ((kk * 64 + kgrp * 16) ^ aswz));
      acc_a = MFMA16(a, wf[kk], acc_a);
    }
#pragma unroll
    for (int kk = 8; kk < 16; ++kk) {   // h part, k = 256..511
      short8 a = *reinterpret_cast<const short8*>(
          sH + arow * 1024 + ((kk * 64 + kgrp * 16) ^ aswz));
      acc_b = MFMA16(a, wf[kk], acc_b);
    }
#pragma unroll
    for (int kk = 0; kk < 4; ++kk) {    // x part, k = 512..639
      short8 a = *reinterpret_cast<const short8*>(
          sX + arow * 512 + ((kk * 64 + kgrp * 16) ^ aswz));
      acc_a = MFMA16(a, wf[16 + kk], acc_a);
    }
#pragma unroll
    for (int kk = 4; kk < 8; ++kk) {    // x part, k = 640..767
      short8 a = *reinterpret_cast<const short8*>(
          sX + arow * 512 + ((kk * 64 + kgrp * 16) ^ aswz));
      acc_b = MFMA16(a, wf[16 + kk], acc_b);
    }
    f32x4 acc;
#pragma unroll
    for (int m = 0; m < 4; ++m) acc[m] = acc_a[m] + acc_b[m];

    // ---- 5. gather gates via 3 shfl_xor rounds (within 16-lane groups):
    // lane cjj<4 ends with i=acc, f=r1, g=r2, o=r3 for its column.
    float r1[4], r2[4], r3[4];
#pragma unroll
    for (int m = 0; m < 4; ++m) {
      r1[m] = __shfl_xor(acc[m], 4);
      r2[m] = __shfl_xor(acc[m], 8);
      r3[m] = __shfl_xor(r1[m], 8);
    }
    if (cjj < 4) {   // 16 productive lanes per wave: 16 rows x this lane's col
#pragma unroll
      for (int m = 0; m < 4; ++m) {
        float ig = sigm(acc[m]), fg = sigm(r1[m]);
        float gg = tanh_(r2[m]), og = sigm(r3[m]);
        float c = fg * cpr[m] + ig * gg;
        cpr[m] = c;
        float hh = og * tanh_(c);
        __hip_bfloat16 hb = __float2bfloat16(hh);
        hstage[kgrp * 4 + m][w * 4 + c4] = *reinterpret_cast<unsigned short*>(&hb);
      }
    }
    __syncthreads();

    // ---- 6. store h slice: 16 rows x 32 cols x 2B (64 threads x 16B;
    // write-through L1 -> shared XCD L2)
    if (tid < 64) {
      int row = tid >> 2, chunk = tid & 3;
      f32x4 v = *reinterpret_cast<const f32x4*>(&hstage[row][chunk * 8]);
      *reinterpret_cast<f32x4*>(
          hwrite + ((size_t)(bg * 16 + row) * Hh + gjw * 32 + chunk * 8) * 2) = v;
    }
    __syncthreads();  // drains vmcnt per wave => h stores complete at L2

    // ---- 7. signal
    if (tid == 0) {
      (void)__hip_atomic_fetch_add(cnt, 1, __ATOMIC_RELAXED,
                                   __HIP_MEMORY_SCOPE_WORKGROUP);
    }

    // ---- 8. refill x for step s+2 (issued a full step before use; latency
    // hidden under the next step's poll + staging + MFMA)
    if (s + 2 <= Tt) {
      xv0 = *reinterpret_cast<const f32x4*>(xbase + (size_t)(s + 1) * Dd);
      xv1 = *reinterpret_cast<const f32x4*>(xbase + (size_t)(s + 1) * Dd + 4);
    }
  };

  for (int s = 1; s <= Tt; s += 2) {
    STEP(s,     xA0, xA1);
    STEP(s + 1, xB0, xB1);
  }
}

__global__ void out_dense(const __hip_bfloat16* __restrict__ hT,
                          const float* __restrict__ Wd,
                          const float* __restrict__ bd,
                          float* __restrict__ out)
{
  // lstm_seq's end-of-kernel release writes dirty L2 back; plain loads ok.
  __shared__ float hrow[Hh];
  int b = blockIdx.x;
  int o = threadIdx.x;
  for (int k = o; k < Hh; k += Oo)
    hrow[k] = __bfloat162float(hT[(size_t)b * Hh + k]);
  __syncthreads();
  float acc = bd[o];
  for (int k = 0; k < Hh; ++k)
    acc = fmaf(hrow[k], Wd[(size_t)k * Oo + o], acc);
  out[(size_t)b * Oo + o] = acc;
}

extern "C" void kernel_launch(void* const* d_in, const int* in_sizes, int n_in,
                              void* d_out, int out_size, void* d_ws, size_t ws_size,
                              hipStream_t stream) {
  (void)in_sizes; (void)n_in; (void)out_size; (void)ws_size;
  const float* X  = (const float*)d_in[0];
  const float* Wi = (const float*)d_in[1];
  const float* Wh = (const float*)d_in[2];
  const float* b  = (const float*)d_in[3];
  const float* Wd = (const float*)d_in[4];
  const float* bd = (const float*)d_in[5];
  float* out = (float*)d_out;

  char* ws = (char*)d_ws;
  int* tickets = (int*)(ws + TICK_OFF);
  int* cnts    = (int*)(ws + CNT_OFF);
  char* hbuf   = ws + HBUF_OFF;

  // zero tickets, counters, and h(0) every launch (graph-replay deterministic)
  hipMemsetAsync(d_ws, 0, WS_ZERO_BYTES, stream);
  lstm_seq<<<NWG_LAUNCH, BLOCK, 0, stream>>>(X, Wi, Wh, b, hbuf, cnts, tickets);
  out_dense<<<Bb, Oo, 0, stream>>>((const __hip_bfloat16*)hbuf, Wd, bd, out);
}

// Round 14
// 2523.219 us; speedup vs baseline: 1.4298x; 1.0536x over previous
//
#include <hip/hip_runtime.h>
#include <hip/hip_bf16.h>

// Problem sizes
#define Bb 128
#define Tt 1024
#define Dd 256
#define Hh 512
#define G4 2048
#define Oo 256

#define NBG 8        // batch groups (16 rows each), one per XCD by construction
#define WPB 16       // worker wgs per batch group (32 h-cols each)
#define NWG_LAUNCH 256  // launch 2x needed; surplus wgs exit after ticket claim
#define BLOCK 512    // 8 waves

#define SPIN_CAP (1u << 16)   // PER-STEP spin cap (with s_sleep backoff)

typedef __attribute__((ext_vector_type(8))) short short8;
typedef __attribute__((ext_vector_type(4))) float f32x4;
typedef unsigned long long u64;

// ws layout: [tickets: 8 x 64B @0][cnt: 8 x 128B @2048][hbuf: 2*128*512 bf16 @4096]
#define TICK_OFF 0
#define CNT_OFF  2048
#define HBUF_OFF 4096
#define WS_ZERO_BYTES (4096 + Bb*Hh*2)   // tickets + counters + hbuf half 0

__device__ __forceinline__ short f2bf(float f) {
  __hip_bfloat16 h = __float2bfloat16(f);
  return *reinterpret_cast<short*>(&h);
}
__device__ __forceinline__ float sigm(float x) {
  return __builtin_amdgcn_rcpf(1.f + __expf(-x));
}
__device__ __forceinline__ float tanh_(float x) {
  return fmaf(2.f, __builtin_amdgcn_rcpf(1.f + __expf(-2.f * x)), -1.f);
}

#define MFMA16(A, B, C) __builtin_amdgcn_mfma_f32_16x16x32_bf16((A), (B), (C), 0, 0, 0)

__global__ __launch_bounds__(BLOCK, 2) void lstm_seq(
    const float* __restrict__ X, const float* __restrict__ Wi,
    const float* __restrict__ Wh, const float* __restrict__ bias,
    char* hbuf, int* cnts, int* tickets)
{
  __shared__ char sH[16 * 1024];            // h tile (bf16, XOR-swizzled)
  __shared__ char sX[16 * 512];             // x tile (bf16, XOR-swizzled)
  __shared__ unsigned short hstage[16][40]; // wg h-slice (16 rows x 32 cols), padded
  __shared__ int sSlot;

  const int tid  = threadIdx.x;
  const int w    = tid >> 6;      // wave 0..7
  const int lane = tid & 63;

  // ---- Role claim: all 16 workers of a bg are on XCD bg BY CONSTRUCTION.
  int myxcc;
  asm volatile("s_getreg_b32 %0, hwreg(HW_REG_XCC_ID)" : "=s"(myxcc));
  myxcc &= 7;
  if (tid == 0) {
    sSlot = __hip_atomic_fetch_add(&tickets[myxcc * 16], 1,
                                   __ATOMIC_RELAXED, __HIP_MEMORY_SCOPE_AGENT);
  }
  __syncthreads();
  const int gjw = sSlot;          // col-group: h-cols [gjw*32, +32)
  if (gjw >= WPB) return;         // surplus wg: exit (wg-uniform)
  const int bg = myxcc;           // batch group == this XCD
  int* cnt = cnts + bg * 32;      // 128B apart per bg

  // ---- Persistent weight B-fragments: ONE n-tile per wave (24 x short8).
  // Lane cjj: gate = cjj>>2, c4 = cjj&3 -> col = gate*Hh + gjw*32 + w*4 + c4.
  // B lane map (16x16x32): col = lane&15, k = kk*32 + (lane>>4)*8 + i
  const int cjj  = lane & 15;
  const int kgrp = lane >> 4;        // 0..3
  const int gate = cjj >> 2;
  const int c4   = cjj & 3;
  const int colg = gate * Hh + gjw * 32 + w * 4 + c4;

  short8 wf[24];
#pragma unroll
  for (int kk = 0; kk < 24; ++kk) {
    short8 f;
#pragma unroll
    for (int i = 0; i < 8; ++i) {
      int k = kk * 32 + kgrp * 8 + i;
      float v = (k < Hh) ? Wh[(size_t)k * G4 + colg]
                         : Wi[(size_t)(k - Hh) * G4 + colg];
      f[i] = f2bf(v);
    }
    wf[kk] = f;
  }
  const float bvv = bias[colg];

  const int arow = cjj;              // MFMA A row
  const int aswz = (arow & 7) << 4;
  float cpr[4] = {0.f, 0.f, 0.f, 0.f};  // c-state rows kgrp*4+m (gate-0 lanes)

  // ---- h-staging mapping, STAGGERED by gjw so the 16 wgs of a bg sweep the
  // 16KB h tile starting at different rows (de-aligns the post-poll L2 burst).
  const int hc0 = (tid + gjw * 64) & 1023;
  const int hc1 = (tid + 512 + gjw * 64) & 1023;
  const int hrow0 = hc0 >> 6, hoff0 = hc0 & 63;
  const int hrow1 = hc1 >> 6, hoff1 = hc1 & 63;

  // ---- x prefetch (2-step pipeline in registers)
  const int xrow = tid >> 5, xseg = tid & 31;   // wg covers 16 rows x 256 f32
  const float* xbase = X + (size_t)(bg * 16 + xrow) * Tt * Dd + xseg * 8;
  f32x4 xA0 = *reinterpret_cast<const f32x4*>(xbase);
  f32x4 xA1 = *reinterpret_cast<const f32x4*>(xbase + 4);
  f32x4 xB0 = *reinterpret_cast<const f32x4*>(xbase + Dd);
  f32x4 xB1 = *reinterpret_cast<const f32x4*>(xbase + Dd + 4);

  auto STEP = [&](int s, f32x4& xv0, f32x4& xv1) {
    const char* hread  = hbuf + (size_t)((s - 1) & 1) * (Bb * Hh * 2);
    char*       hwrite = hbuf + (size_t)(s & 1) * (Bb * Hh * 2);

    // ---- 1. stage x_t into sX from regs prefetched 2 steps ago
    {
      short8 xb;
      xb[0] = f2bf(xv0[0]); xb[1] = f2bf(xv0[1]); xb[2] = f2bf(xv0[2]); xb[3] = f2bf(xv0[3]);
      xb[4] = f2bf(xv1[0]); xb[5] = f2bf(xv1[1]); xb[6] = f2bf(xv1[2]); xb[7] = f2bf(xv1[3]);
      *reinterpret_cast<short8*>(sX + xrow * 512 + ((xseg * 16) ^ ((xrow & 7) << 4))) = xb;
    }
    __syncthreads();   // sX handoff

    // ---- 2. x-part MFMA (k = 512..767) — independent of h; overlaps the
    // producer wait (other waves compute while tid0's wave reaches the poll).
    f32x4 acc_a, acc_b;
#pragma unroll
    for (int m = 0; m < 4; ++m) { acc_a[m] = bvv; acc_b[m] = 0.f; }
#pragma unroll
    for (int kk = 0; kk < 4; ++kk) {
      short8 a = *reinterpret_cast<const short8*>(
          sX + arow * 512 + ((kk * 64 + kgrp * 16) ^ aswz));
      acc_a = MFMA16(a, wf[16 + kk], acc_a);
    }
#pragma unroll
    for (int kk = 4; kk < 8; ++kk) {
      short8 a = *reinterpret_cast<const short8*>(
          sX + arow * 512 + ((kk * 64 + kgrp * 16) ^ aswz));
      acc_b = MFMA16(a, wf[16 + kk], acc_b);
    }

    // ---- 3. wait for the 16 producers of this bg (step s-1). Non-idempotent
    // RMW executes at the XCD L2 atomic point; s_sleep backoff keeps the flag
    // line free. PER-STEP spin cap.
    if (s > 1 && tid == 0) {
      const int tgt = WPB * (s - 1);
      unsigned spin = 0;
      while ((int)(__hip_atomic_fetch_add((unsigned*)cnt, 0x10000u,
                                          __ATOMIC_RELAXED,
                                          __HIP_MEMORY_SCOPE_WORKGROUP) & 0xFFFFu) < tgt
             && ++spin < SPIN_CAP) {
        __builtin_amdgcn_s_sleep(1);
      }
    }
    __syncthreads();

    // ---- 4. invalidate L1 (stale h lines from step s-2), cooperative
    // coalesced h(s-1) staging (staggered start): 16KB from XCD L2.
    asm volatile("buffer_inv sc0" ::: "memory");
    {
      f32x4 v0 = *reinterpret_cast<const f32x4*>(
          hread + (size_t)(bg * 16 + hrow0) * 1024 + hoff0 * 16);
      f32x4 v1 = *reinterpret_cast<const f32x4*>(
          hread + (size_t)(bg * 16 + hrow1) * 1024 + hoff1 * 16);
      *reinterpret_cast<f32x4*>(
          sH + hrow0 * 1024 + ((hoff0 * 16) ^ ((hrow0 & 7) << 4))) = v0;
      *reinterpret_cast<f32x4*>(
          sH + hrow1 * 1024 + ((hoff1 * 16) ^ ((hrow1 & 7) << 4))) = v1;
    }
    __syncthreads();

    // ---- 5. h-part MFMA (k = 0..511), two independent acc chains
#pragma unroll
    for (int kk = 0; kk < 8; ++kk) {
      short8 a = *reinterpret_cast<const short8*>(
          sH + arow * 1024 + ((kk * 64 + kgrp * 16) ^ aswz));
      acc_a = MFMA16(a, wf[kk], acc_a);
    }
#pragma unroll
    for (int kk = 8; kk < 16; ++kk) {
      short8 a = *reinterpret_cast<const short8*>(
          sH + arow * 1024 + ((kk * 64 + kgrp * 16) ^ aswz));
      acc_b = MFMA16(a, wf[kk], acc_b);
    }
    f32x4 acc;
#pragma unroll
    for (int m = 0; m < 4; ++m) acc[m] = acc_a[m] + acc_b[m];

    // ---- 6. gather gates via 3 shfl_xor rounds (within 16-lane groups):
    // lane cjj<4 ends with i=acc, f=r1, g=r2, o=r3 for its column.
    float r1[4], r2[4], r3[4];
#pragma unroll
    for (int m = 0; m < 4; ++m) {
      r1[m] = __shfl_xor(acc[m], 4);
      r2[m] = __shfl_xor(acc[m], 8);
      r3[m] = __shfl_xor(r1[m], 8);
    }
    if (cjj < 4) {   // 16 productive lanes per wave: 16 rows x this lane's col
#pragma unroll
      for (int m = 0; m < 4; ++m) {
        float ig = sigm(acc[m]), fg = sigm(r1[m]);
        float gg = tanh_(r2[m]), og = sigm(r3[m]);
        float c = fg * cpr[m] + ig * gg;
        cpr[m] = c;
        float hh = og * tanh_(c);
        __hip_bfloat16 hb = __float2bfloat16(hh);
        hstage[kgrp * 4 + m][w * 4 + c4] = *reinterpret_cast<unsigned short*>(&hb);
      }
    }
    __syncthreads();

    // ---- 7. store h slice (wave 0 only: 64 threads x 16B, coalesced;
    // write-through L1 -> shared XCD L2), wave-local drain, signal.
    // No trailing full-wg barrier: other waves proceed to stage-x of s+1;
    // sX/hstage reuse is gated by s+1's barriers, which wave 0 also crosses.
    if (tid < 64) {
      int row = tid >> 2, chunk = tid & 3;
      f32x4 v = *reinterpret_cast<const f32x4*>(&hstage[row][chunk * 8]);
      *reinterpret_cast<f32x4*>(
          hwrite + ((size_t)(bg * 16 + row) * Hh + gjw * 32 + chunk * 8) * 2) = v;
      asm volatile("s_waitcnt vmcnt(0)" ::: "memory");  // wave-0 stores at L2
      if (tid == 0) {
        (void)__hip_atomic_fetch_add(cnt, 1, __ATOMIC_RELAXED,
                                     __HIP_MEMORY_SCOPE_WORKGROUP);
      }
    }

    // ---- 8. refill x for step s+2 (latency hidden under the next step)
    if (s + 2 <= Tt) {
      xv0 = *reinterpret_cast<const f32x4*>(xbase + (size_t)(s + 1) * Dd);
      xv1 = *reinterpret_cast<const f32x4*>(xbase + (size_t)(s + 1) * Dd + 4);
    }
  };

  for (int s = 1; s <= Tt; s += 2) {
    STEP(s,     xA0, xA1);
    STEP(s + 1, xB0, xB1);
  }
}

__global__ void out_dense(const __hip_bfloat16* __restrict__ hT,
                          const float* __restrict__ Wd,
                          const float* __restrict__ bd,
                          float* __restrict__ out)
{
  // lstm_seq's end-of-kernel release writes dirty L2 back; plain loads ok.
  __shared__ float hrow[Hh];
  int b = blockIdx.x;
  int o = threadIdx.x;
  for (int k = o; k < Hh; k += Oo)
    hrow[k] = __bfloat162float(hT[(size_t)b * Hh + k]);
  __syncthreads();
  float acc = bd[o];
  for (int k = 0; k < Hh; ++k)
    acc = fmaf(hrow[k], Wd[(size_t)k * Oo + o], acc);
  out[(size_t)b * Oo + o] = acc;
}

extern "C" void kernel_launch(void* const* d_in, const int* in_sizes, int n_in,
                              void* d_out, int out_size, void* d_ws, size_t ws_size,
                              hipStream_t stream) {
  (void)in_sizes; (void)n_in; (void)out_size; (void)ws_size;
  const float* X  = (const float*)d_in[0];
  const float* Wi = (const float*)d_in[1];
  const float* Wh = (const float*)d_in[2];
  const float* b  = (const float*)d_in[3];
  const float* Wd = (const float*)d_in[4];
  const float* bd = (const float*)d_in[5];
  float* out = (float*)d_out;

  char* ws = (char*)d_ws;
  int* tickets = (int*)(ws + TICK_OFF);
  int* cnts    = (int*)(ws + CNT_OFF);
  char* hbuf   = ws + HBUF_OFF;

  // zero tickets, counters, and h(0) every launch (graph-replay deterministic)
  hipMemsetAsync(d_ws, 0, WS_ZERO_BYTES, stream);
  lstm_seq<<<NWG_LAUNCH, BLOCK, 0, stream>>>(X, Wi, Wh, b, hbuf, cnts, tickets);
  out_dense<<<Bb, Oo, 0, stream>>>((const __hip_bfloat16*)hbuf, Wd, bd, out);
}